// Round 10
// baseline (43.947 us; speedup 1.0000x reference)
//
#include <hip/hip_runtime.h>

#define T_LEN 32768
#define F_DIM 758
#define IN_SZ 730
#define CHUNK_L 16
#define WARM_W 64
#define N_CHUNK (T_LEN / CHUNK_L)    // 2048 chunks
#define SCAN_BLOCKS (N_CHUNK / 64)   // 32 blocks x 64 lanes
#define STAGE_ROWS 1088              // 64 warm-up + 1024 output rows per block

#define PAIRS (T_LEN / 2)            // 16384 2-row superperiods (379 float4 each)
#define GEMV_BLOCKS 1024
#define PAIRS_PER_BLOCK (PAIRS / GEMV_BLOCKS)   // 16

// Kernel 1: xp = x[:, :730] @ W^T fused with bias and exp2-domain prescale.
// Memcpy-granularity loads: a 2-row superperiod is EXACTLY 379 float4s
// (1516 floats), so lane<->(row,k) is compile-time fixed. Each wave-load is
// 64 lanes x 16 B contiguous distinct = 1 KB/instr — the exact pattern that
// hits 6.3+ TB/s in copy/fill. Block = 4 waves; wave g handles gate g (same
// x data, L1-merged); per-lane weights split wA/wB for even/odd row of the
// pair (zero at k>=730 and across the straddle). 12-shuffle butterfly; lane 0
// stores 2 dwords. Double-buffered pair prefetch, ~110 VGPR.
__global__ __launch_bounds__(256) void gemv_gates(
    const float* __restrict__ x, const float* __restrict__ w,
    const float* __restrict__ bias, float* __restrict__ xpw) {
  const float L2E = 1.4426950408889634f;
  int tid  = threadIdx.x;
  int lane = tid & 63;
  int g    = tid >> 6;                  // wave index == gate 0..3

  // ---- fixed per-lane weights for the 2-row superperiod ----
  const float* wg = w + (size_t)g * IN_SZ;
  float wA[6][4], wB[6][4];
#pragma unroll
  for (int s = 0; s < 6; s++) {
    int q = lane + 64 * s;
#pragma unroll
    for (int e = 0; e < 4; e++) {
      int idx = 4 * q + e;              // flat element in pair, 0..1535
      int r01 = idx / 758;
      int k   = idx - 758 * r01;
      float val = (q < 379 && r01 < 2 && k < IN_SZ) ? wg[k] : 0.f;
      wA[s][e] = (r01 == 0) ? val : 0.f;
      wB[s][e] = (r01 == 1) ? val : 0.f;
    }
  }
  float bg = bias[g];
  float cg = (g == 3) ? (-2.f * L2E) : (-L2E);

  const float4 z4 = {0.f, 0.f, 0.f, 0.f};
  float4 xa[6], xb[6];

  auto loadpair = [&](float4* dst, int pr) {
    const float4* src = (const float4*)x + (size_t)pr * 379;
#pragma unroll
    for (int s = 0; s < 6; s++) {
      int q = lane + 64 * s;
      dst[s] = (q < 379) ? src[q] : z4;     // 1 KB contiguous distinct per instr
    }
  };
  auto dotpair = [&](const float4* v, float& rA, float& rB) {
    float sA = 0.f, sB = 0.f;
#pragma unroll
    for (int s = 0; s < 6; s++) {
#pragma unroll
      for (int e = 0; e < 4; e++) {
        float xv = ((const float*)&v[s])[e];
        sA = fmaf(xv, wA[s][e], sA);
        sB = fmaf(xv, wB[s][e], sB);
      }
    }
#pragma unroll
    for (int off = 1; off < 64; off <<= 1) {
      sA += __shfl_xor(sA, off);
      sB += __shfl_xor(sB, off);
    }
    rA = sA; rB = sB;
  };
  auto emit = [&](int pr, float sA, float sB) {
    if (lane == 0) {
      xpw[(size_t)(2 * pr) * 4 + g]     = cg * (sA + bg);
      xpw[(size_t)(2 * pr + 1) * 4 + g] = cg * (sB + bg);
    }
  };

  int p0 = blockIdx.x;                  // grid-strided contiguous sweep
  loadpair(xa, p0);
  loadpair(xb, p0 + GEMV_BLOCKS);
#pragma unroll
  for (int r = 0; r < PAIRS_PER_BLOCK; r += 2) {
    float sA, sB;
    dotpair(xa, sA, sB);
    if (r + 2 < PAIRS_PER_BLOCK) loadpair(xa, p0 + (r + 2) * GEMV_BLOCKS);
    emit(p0 + r * GEMV_BLOCKS, sA, sB);
    dotpair(xb, sA, sB);
    if (r + 3 < PAIRS_PER_BLOCK) loadpair(xb, p0 + (r + 3) * GEMV_BLOCKS);
    emit(p0 + (r + 1) * GEMV_BLOCKS, sA, sB);
  }
}

// 16-row rotation swizzle: staging writes and per-step strided reads both
// spread 64 lanes uniformly over the 8 b128 bank-slots (the LDS b128 floor).
__device__ __forceinline__ int phys(int r) {
  return (r & ~15) | ((r + (r >> 4)) & 15);
}

// Kernel 2 (UNCHANGED since round 6): chunk-parallel LSTM scan, inputs staged
// in LDS, 4-deep ds_read prefetch ring. One 16-step chunk per lane, 64-step
// warm-up (contractive recurrence, min decay ~ e^-32).
__global__ __launch_bounds__(64) void lstm_scan(
    const float* __restrict__ xpw, const float* __restrict__ wr,
    const float* __restrict__ rgw, const float* __restrict__ rgb,
    const float* __restrict__ h0p, const float* __restrict__ c0p,
    float* __restrict__ out) {
  const float L2E = 1.4426950408889634f;
  const float M2  = -2.f * L2E;
  __shared__ float4 lds_xp[STAGE_ROWS];
  __shared__ float  lds_h[64][17];
  __shared__ float  lds_c[64][17];

  int lane = threadIdx.x;
  int B0   = blockIdx.x * (64 * CHUNK_L);
  int R0   = B0 - WARM_W; if (R0 < 0) R0 = 0;

  const float4* xp4 = (const float4*)xpw;
#pragma unroll
  for (int i = 0; i < STAGE_ROWS / 64; i++) {
    int r = 64 * i + lane;
    lds_xp[phys(r)] = xp4[R0 + r];
  }
  __syncthreads();

  float w20 = -L2E * wr[0];
  float w21 = -L2E * wr[1];
  float w22 = -L2E * wr[2];
  float w23 = -2.f * L2E * wr[3];

  float h = h0p[0], c = c0p[0];

  auto stepc = [&](float4 p) {
    float u0 = fmaf(h, w20, p.x);
    float u1 = fmaf(h, w21, p.y);
    float u2 = fmaf(h, w22, p.z);
    float u3 = fmaf(h, w23, p.w);
    float f  = __builtin_amdgcn_rcpf(1.f + __builtin_amdgcn_exp2f(u0));
    float i  = __builtin_amdgcn_rcpf(1.f + __builtin_amdgcn_exp2f(u1));
    float o  = __builtin_amdgcn_rcpf(1.f + __builtin_amdgcn_exp2f(u2));
    float r3 = __builtin_amdgcn_rcpf(1.f + __builtin_amdgcn_exp2f(u3));
    c = fmaf(f, c, fmaf(2.f * i, r3, -i));           // c = f*c + i*(2*r3-1)
    float rt = __builtin_amdgcn_rcpf(1.f + __builtin_amdgcn_exp2f(c * M2));
    h = fmaf(2.f * o, rt, -o);                       // h = o*tanh(c)
  };

  auto XP = [&](int r) {
    int rc = r < 0 ? 0 : (r > STAGE_ROWS - 1 ? STAGE_ROWS - 1 : r);
    return lds_xp[phys(rc)];
  };

  int start = B0 + lane * CHUNK_L;      // global first output step
  int rr = (start - WARM_W) - R0;       // LDS row index (negative only in block 0)

  float4 p0 = XP(rr), p1 = XP(rr + 1), p2 = XP(rr + 2), p3 = XP(rr + 3);

  for (int s = 0; s < WARM_W; s += 4, rr += 4) {
    float4 n0 = XP(rr + 4), n1 = XP(rr + 5), n2 = XP(rr + 6), n3 = XP(rr + 7);
    if (rr     >= 0) stepc(p0);
    if (rr + 1 >= 0) stepc(p1);
    if (rr + 2 >= 0) stepc(p2);
    if (rr + 3 >= 0) stepc(p3);
    p0 = n0; p1 = n1; p2 = n2; p3 = n3;
  }
#pragma unroll
  for (int gq = 0; gq < CHUNK_L; gq += 4, rr += 4) {
    float4 n0 = XP(rr + 4), n1 = XP(rr + 5), n2 = XP(rr + 6), n3 = XP(rr + 7);
    stepc(p0); lds_h[lane][gq + 0] = h; lds_c[lane][gq + 0] = c;
    stepc(p1); lds_h[lane][gq + 1] = h; lds_c[lane][gq + 1] = c;
    stepc(p2); lds_h[lane][gq + 2] = h; lds_c[lane][gq + 2] = c;
    stepc(p3); lds_h[lane][gq + 3] = h; lds_c[lane][gq + 3] = c;
    p0 = n0; p1 = n1; p2 = n2; p3 = n3;
  }
  __syncthreads();

  float* outq = out;                      // q_t : [0, 32768)
  float* outh = out + T_LEN;              // h_n : [32768, 65537)
  float* outc = out + 2 * T_LEN + 1;      // c_n : [65537, 98306)
  float rw = rgw[0], rb = rgb[0];
#pragma unroll
  for (int k = 0; k < CHUNK_L; k++) {
    int idx = lane + 64 * k;
    float hv = lds_h[idx >> 4][idx & 15];
    float cv = lds_c[idx >> 4][idx & 15];
    outq[B0 + idx]     = fmaf(hv, rw, rb);
    outh[B0 + idx + 1] = hv;
    outc[B0 + idx + 1] = cv;
  }
  if (blockIdx.x == 0 && lane == 0) { outh[0] = h0p[0]; outc[0] = c0p[0]; }
}

extern "C" void kernel_launch(void* const* d_in, const int* in_sizes, int n_in,
                              void* d_out, int out_size, void* d_ws, size_t ws_size,
                              hipStream_t stream) {
  const float* x  = (const float*)d_in[0];
  const float* wi = (const float*)d_in[1];
  const float* wr = (const float*)d_in[2];
  const float* bs = (const float*)d_in[3];
  const float* rw = (const float*)d_in[4];
  const float* rb = (const float*)d_in[5];
  const float* h0 = (const float*)d_in[6];
  const float* c0 = (const float*)d_in[7];
  float* out = (float*)d_out;
  float* xpw = (float*)d_ws;   // (T_LEN x 4) f32 = 512 KB scratch

  gemv_gates<<<GEMV_BLOCKS, 256, 0, stream>>>(x, wi, bs, xpw);
  lstm_scan<<<SCAN_BLOCKS, 64, 0, stream>>>(xpw, wr, rw, rb, h0, c0, out);
}

// Round 11
// 35.303 us; speedup vs baseline: 1.2448x; 1.2448x over previous
//
#include <hip/hip_runtime.h>

#define T_LEN 32768
#define F_DIM 758
#define IN_SZ 730
#define CHUNK_L 16
#define WARM_W 64
#define N_CHUNK (T_LEN / CHUNK_L)    // 2048 chunks
#define SCAN_BLOCKS (N_CHUNK / 64)   // 32 blocks x 64 lanes
#define STAGE_ROWS 1088              // 64 warm-up + 1024 output rows per block

#define PAIRS 16384                  // 2-row superperiods: 6064 B = 379 float4, 16B-aligned
#define GEMV_BLOCKS 1024             // x 512 threads = 8192 waves, 2 pairs/wave
#define WAVES_TOTAL (GEMV_BLOCKS * 8)

__device__ __forceinline__ float dot4(float4 a, float4 b, float acc) {
  acc = fmaf(a.x, b.x, acc);
  acc = fmaf(a.y, b.y, acc);
  acc = fmaf(a.z, b.z, acc);
  return fmaf(a.w, b.w, acc);
}

// Kernel 1: xp = x[:, :730] @ W^T fused with bias and exp2-domain prescale.
// One WAVE per 2-row pair: 6 x dwordx4 loads, each 64 lanes x 16 B contiguous
// DISTINCT (1 KB/instr, memcpy pattern, no replication). Weights in LDS as two
// zero-masked pair-position arrays (wp0 = row0-masked, wp1 = row1-masked) so
// the row straddle at chunk 189 routes itself: k>=730 and f<758 slots are 0.
// Lane-contiguous ds_read_b128 (conflict-free). ~60-75 VGPR -> 16-32 waves/CU:
// latency hidden by TLP, no manual prefetch. Reduce = 27 shuffles.
__global__ __launch_bounds__(512) void gemv_gates(
    const float* __restrict__ x, const float* __restrict__ w,
    const float* __restrict__ bias, float* __restrict__ xpw) {
  const float L2E = 1.4426950408889634f;
  __shared__ float4 wp0[4][192];   // gate g, chunk q<192: els 4q+e -> row0 k=4q+e (0 if k>=730)
  __shared__ float4 wp1[4][384];   // gate g, chunk q<384: els f=4q+e -> row1 k=f-758 (0 outside)
  int tid  = threadIdx.x;
  int lane = tid & 63;

  for (int q = tid; q < 768; q += 512) {
    int g = q / 192, c = q - 192 * g;
    float4 v;
#pragma unroll
    for (int e = 0; e < 4; e++) {
      int k = 4 * c + e;
      ((float*)&v)[e] = (k < IN_SZ) ? w[g * IN_SZ + k] : 0.f;
    }
    wp0[g][c] = v;
  }
  for (int q = tid; q < 1536; q += 512) {
    int g = q / 384, c = q - 384 * g;
    float4 v;
#pragma unroll
    for (int e = 0; e < 4; e++) {
      int f = 4 * c + e;
      ((float*)&v)[e] = (f >= F_DIM && f < F_DIM + IN_SZ) ? w[g * IN_SZ + (f - F_DIM)] : 0.f;
    }
    wp1[g][c] = v;
  }
  __syncthreads();

  int wid = blockIdx.x * 8 + (tid >> 6);
#pragma unroll
  for (int it = 0; it < 2; it++) {
    int pr = wid + it * WAVES_TOTAL;
    const float4* src = (const float4*)x + (size_t)pr * 379;
    float4 xv[6];
#pragma unroll
    for (int m = 0; m < 6; m++) {
      int q = lane + 64 * m;
      if (q > 378) q = 378;          // tail lanes: weights there are 0
      xv[m] = src[q];
    }
    float a0[4] = {0.f, 0.f, 0.f, 0.f};
    float a1[4] = {0.f, 0.f, 0.f, 0.f};
#pragma unroll
    for (int g = 0; g < 4; g++) {
      const float4* p0 = wp0[g];
      const float4* p1 = wp1[g];
      a0[g] = dot4(xv[0], p0[lane],       a0[g]);
      a0[g] = dot4(xv[1], p0[lane + 64],  a0[g]);
      a0[g] = dot4(xv[2], p0[lane + 128], a0[g]);   // straddle: row0 part
      a1[g] = dot4(xv[2], p1[lane + 128], a1[g]);   // straddle: row1 part
      a1[g] = dot4(xv[3], p1[lane + 192], a1[g]);
      a1[g] = dot4(xv[4], p1[lane + 256], a1[g]);
      a1[g] = dot4(xv[5], p1[lane + 320], a1[g]);
    }
    // ---- reduce: low-offset butterfly, per-lane gate select, high-offset ----
#pragma unroll
    for (int off = 1; off <= 4; off <<= 1) {
#pragma unroll
      for (int g = 0; g < 4; g++) {
        a0[g] += __shfl_xor(a0[g], off);
        a1[g] += __shfl_xor(a1[g], off);
      }
    }
    int g = lane & 3, r = (lane >> 2) & 1;
    float s0 = (g == 0) ? a0[0] : (g == 1) ? a0[1] : (g == 2) ? a0[2] : a0[3];
    float s1 = (g == 0) ? a1[0] : (g == 1) ? a1[1] : (g == 2) ? a1[2] : a1[3];
    float s  = r ? s1 : s0;
    s += __shfl_xor(s, 8);
    s += __shfl_xor(s, 16);
    s += __shfl_xor(s, 32);
    if (lane < 8) {
      float bg = bias[g];
      float cg = (g == 3) ? (-2.f * L2E) : (-L2E);
      xpw[(size_t)(2 * pr + r) * 4 + g] = cg * (s + bg);
    }
  }
}

// 16-row rotation swizzle: staging writes and per-step strided reads both
// spread 64 lanes uniformly over the 8 b128 bank-slots (the LDS b128 floor).
__device__ __forceinline__ int phys(int r) {
  return (r & ~15) | ((r + (r >> 4)) & 15);
}

// Kernel 2 (UNCHANGED since round 6): chunk-parallel LSTM scan, inputs staged
// in LDS, 4-deep ds_read prefetch ring. One 16-step chunk per lane, 64-step
// warm-up (contractive recurrence, min decay ~ e^-32).
__global__ __launch_bounds__(64) void lstm_scan(
    const float* __restrict__ xpw, const float* __restrict__ wr,
    const float* __restrict__ rgw, const float* __restrict__ rgb,
    const float* __restrict__ h0p, const float* __restrict__ c0p,
    float* __restrict__ out) {
  const float L2E = 1.4426950408889634f;
  const float M2  = -2.f * L2E;
  __shared__ float4 lds_xp[STAGE_ROWS];
  __shared__ float  lds_h[64][17];
  __shared__ float  lds_c[64][17];

  int lane = threadIdx.x;
  int B0   = blockIdx.x * (64 * CHUNK_L);
  int R0   = B0 - WARM_W; if (R0 < 0) R0 = 0;

  const float4* xp4 = (const float4*)xpw;
#pragma unroll
  for (int i = 0; i < STAGE_ROWS / 64; i++) {
    int r = 64 * i + lane;
    lds_xp[phys(r)] = xp4[R0 + r];
  }
  __syncthreads();

  float w20 = -L2E * wr[0];
  float w21 = -L2E * wr[1];
  float w22 = -L2E * wr[2];
  float w23 = -2.f * L2E * wr[3];

  float h = h0p[0], c = c0p[0];

  auto stepc = [&](float4 p) {
    float u0 = fmaf(h, w20, p.x);
    float u1 = fmaf(h, w21, p.y);
    float u2 = fmaf(h, w22, p.z);
    float u3 = fmaf(h, w23, p.w);
    float f  = __builtin_amdgcn_rcpf(1.f + __builtin_amdgcn_exp2f(u0));
    float i  = __builtin_amdgcn_rcpf(1.f + __builtin_amdgcn_exp2f(u1));
    float o  = __builtin_amdgcn_rcpf(1.f + __builtin_amdgcn_exp2f(u2));
    float r3 = __builtin_amdgcn_rcpf(1.f + __builtin_amdgcn_exp2f(u3));
    c = fmaf(f, c, fmaf(2.f * i, r3, -i));           // c = f*c + i*(2*r3-1)
    float rt = __builtin_amdgcn_rcpf(1.f + __builtin_amdgcn_exp2f(c * M2));
    h = fmaf(2.f * o, rt, -o);                       // h = o*tanh(c)
  };

  auto XP = [&](int r) {
    int rc = r < 0 ? 0 : (r > STAGE_ROWS - 1 ? STAGE_ROWS - 1 : r);
    return lds_xp[phys(rc)];
  };

  int start = B0 + lane * CHUNK_L;      // global first output step
  int rr = (start - WARM_W) - R0;       // LDS row index (negative only in block 0)

  float4 p0 = XP(rr), p1 = XP(rr + 1), p2 = XP(rr + 2), p3 = XP(rr + 3);

  for (int s = 0; s < WARM_W; s += 4, rr += 4) {
    float4 n0 = XP(rr + 4), n1 = XP(rr + 5), n2 = XP(rr + 6), n3 = XP(rr + 7);
    if (rr     >= 0) stepc(p0);
    if (rr + 1 >= 0) stepc(p1);
    if (rr + 2 >= 0) stepc(p2);
    if (rr + 3 >= 0) stepc(p3);
    p0 = n0; p1 = n1; p2 = n2; p3 = n3;
  }
#pragma unroll
  for (int gq = 0; gq < CHUNK_L; gq += 4, rr += 4) {
    float4 n0 = XP(rr + 4), n1 = XP(rr + 5), n2 = XP(rr + 6), n3 = XP(rr + 7);
    stepc(p0); lds_h[lane][gq + 0] = h; lds_c[lane][gq + 0] = c;
    stepc(p1); lds_h[lane][gq + 1] = h; lds_c[lane][gq + 1] = c;
    stepc(p2); lds_h[lane][gq + 2] = h; lds_c[lane][gq + 2] = c;
    stepc(p3); lds_h[lane][gq + 3] = h; lds_c[lane][gq + 3] = c;
    p0 = n0; p1 = n1; p2 = n2; p3 = n3;
  }
  __syncthreads();

  float* outq = out;                      // q_t : [0, 32768)
  float* outh = out + T_LEN;              // h_n : [32768, 65537)
  float* outc = out + 2 * T_LEN + 1;      // c_n : [65537, 98306)
  float rw = rgw[0], rb = rgb[0];
#pragma unroll
  for (int k = 0; k < CHUNK_L; k++) {
    int idx = lane + 64 * k;
    float hv = lds_h[idx >> 4][idx & 15];
    float cv = lds_c[idx >> 4][idx & 15];
    outq[B0 + idx]     = fmaf(hv, rw, rb);
    outh[B0 + idx + 1] = hv;
    outc[B0 + idx + 1] = cv;
  }
  if (blockIdx.x == 0 && lane == 0) { outh[0] = h0p[0]; outc[0] = c0p[0]; }
}

extern "C" void kernel_launch(void* const* d_in, const int* in_sizes, int n_in,
                              void* d_out, int out_size, void* d_ws, size_t ws_size,
                              hipStream_t stream) {
  const float* x  = (const float*)d_in[0];
  const float* wi = (const float*)d_in[1];
  const float* wr = (const float*)d_in[2];
  const float* bs = (const float*)d_in[3];
  const float* rw = (const float*)d_in[4];
  const float* rb = (const float*)d_in[5];
  const float* h0 = (const float*)d_in[6];
  const float* c0 = (const float*)d_in[7];
  float* out = (float*)d_out;
  float* xpw = (float*)d_ws;   // (T_LEN x 4) f32 = 512 KB scratch

  gemv_gates<<<GEMV_BLOCKS, 512, 0, stream>>>(x, wi, bs, xpw);
  lstm_scan<<<SCAN_BLOCKS, 64, 0, stream>>>(xpw, wr, rw, rb, h0, c0, out);
}

// Round 12
// 34.010 us; speedup vs baseline: 1.2922x; 1.0380x over previous
//
#include <hip/hip_runtime.h>

#define T_LEN 32768
#define F_DIM 758
#define IN_SZ 730
#define CHUNK_L 16
#define WARM_W 64
#define N_CHUNK (T_LEN / CHUNK_L)    // 2048 chunks
#define SCAN_BLOCKS (N_CHUNK / 64)   // 32 blocks x 64 lanes
#define STAGE_ROWS 1088              // 64 warm-up + 1024 output rows per block

#define GEMV_BLOCKS 512
#define BATCHES 8                    // per block
#define B_CHUNKS 1516                // 4 pairs x 379 float4 = 24256 B per batch
#define X_CHUNKS 6209536             // total float4 in x (32768*758/4)

// Kernel 1: xp = x[:, :730] @ W^T fused with bias and exp2-domain prescale.
// Staging uses the async DMA path: __builtin_amdgcn_global_load_lds width=16,
// 6 per thread per 24 KB batch (lane-consecutive 16 B = memcpy pattern), into
// a double-buffered LDS batch (48 KB -> 3 blocks/CU). Loads cost zero VGPRs
// and queue deep; they drain at the next __syncthreads (vmcnt(0)+barrier).
// Compute: wave w owns row-pair w of the batch; gate-interleaved lanes
// (lane=4p+g), register-persistent weights, row0 via ds_read_b128 (16B
// aligned), row1 via ds_read_b64 pairs (pair straddle is 8B aligned),
// 4-shuffle reduce, lanes 0-3 store.
__global__ __launch_bounds__(256) void gemv_gates(
    const float* __restrict__ x, const float* __restrict__ w,
    const float* __restrict__ bias, float* __restrict__ xpw) {
  const float L2E = 1.4426950408889634f;
  __shared__ float4 xbuf[2][1536];     // 2 x 24576 B
  int tid  = threadIdx.x;
  int lane = tid & 63;
  int g    = lane & 3;                 // gate
  int p    = lane >> 2;                // k-slice 0..15
  int wv_i = tid >> 6;                 // wave 0..3 == pair-in-batch

  // ---- persistent per-lane weight slice (48 VGPR), zero-padded ----
  const float* wg = w + (size_t)g * IN_SZ;
  float4 wv[12];
#pragma unroll
  for (int j = 0; j < 12; j++) {
    int c = p + 16 * j;
#pragma unroll
    for (int e = 0; e < 4; e++) {
      int k = 4 * c + e;
      ((float*)&wv[j])[e] = (c < 183 && k < IN_SZ) ? wg[k] : 0.f;
    }
  }
  float bg = bias[g];
  float cg = (g == 3) ? (-2.f * L2E) : (-L2E);

  const float4* xg = (const float4*)x;

  auto stage = [&](int b, int buf) {
    size_t base = ((size_t)blockIdx.x * BATCHES + b) * B_CHUNKS;
#pragma unroll
    for (int s = 0; s < 6; s++) {
      int q = tid + 256 * s;                 // 0..1535
      size_t gi = base + (size_t)q;
      if (gi > X_CHUNKS - 1) gi = X_CHUNKS - 1;   // clamp at x end (pad slots)
      __builtin_amdgcn_global_load_lds(
          (const __attribute__((address_space(1))) unsigned int*)(xg + gi),
          (__attribute__((address_space(3))) unsigned int*)(&xbuf[buf][q]),
          16, 0, 0);
    }
  };

  auto compute = [&](int b, int buf) {
    int P = (blockIdx.x * BATCHES + b) * 4 + wv_i;      // global pair index
    const float4* pb4 = &xbuf[buf][wv_i * 379];
    const float2* pb2 = (const float2*)pb4;
    float s0 = 0.f, s1 = 0.f;
#pragma unroll
    for (int j = 0; j < 12; j++) {
      int c = p + 16 * j;
      if (c < 183) {
        float4 v = pb4[c];                              // row0, 16B aligned
        s0 = fmaf(v.x, wv[j].x, s0);
        s0 = fmaf(v.y, wv[j].y, s0);
        s0 = fmaf(v.z, wv[j].z, s0);
        s0 = fmaf(v.w, wv[j].w, s0);
        float2 lo = pb2[379 + 2 * c];                   // row1 = floats 758+4c..
        float2 hi = pb2[379 + 2 * c + 1];
        s1 = fmaf(lo.x, wv[j].x, s1);
        s1 = fmaf(lo.y, wv[j].y, s1);
        s1 = fmaf(hi.x, wv[j].z, s1);
        s1 = fmaf(hi.y, wv[j].w, s1);
      }
    }
    // reduce over slice bits (lane bits 2..5)
#pragma unroll
    for (int off = 4; off < 64; off <<= 1) {
      s0 += __shfl_xor(s0, off);
      s1 += __shfl_xor(s1, off);
    }
    if (lane < 4) {
      xpw[(size_t)(2 * P) * 4 + g]     = cg * (s0 + bg);
      xpw[(size_t)(2 * P + 1) * 4 + g] = cg * (s1 + bg);
    }
  };

  stage(0, 0);
  __syncthreads();                       // vmcnt(0): batch 0 resident
#pragma unroll
  for (int b = 0; b < BATCHES; b++) {
    int buf = b & 1;
    if (b + 1 < BATCHES) stage(b + 1, buf ^ 1);   // async, in flight over compute
    compute(b, buf);
    __syncthreads();                     // drains loads + LDS reads
  }
}

// 16-row rotation swizzle: staging writes and per-step strided reads both
// spread 64 lanes uniformly over the 8 b128 bank-slots (the LDS b128 floor).
__device__ __forceinline__ int phys(int r) {
  return (r & ~15) | ((r + (r >> 4)) & 15);
}

// Kernel 2 (UNCHANGED since round 6): chunk-parallel LSTM scan, inputs staged
// in LDS, 4-deep ds_read prefetch ring. One 16-step chunk per lane, 64-step
// warm-up (contractive recurrence, min decay ~ e^-32).
__global__ __launch_bounds__(64) void lstm_scan(
    const float* __restrict__ xpw, const float* __restrict__ wr,
    const float* __restrict__ rgw, const float* __restrict__ rgb,
    const float* __restrict__ h0p, const float* __restrict__ c0p,
    float* __restrict__ out) {
  const float L2E = 1.4426950408889634f;
  const float M2  = -2.f * L2E;
  __shared__ float4 lds_xp[STAGE_ROWS];
  __shared__ float  lds_h[64][17];
  __shared__ float  lds_c[64][17];

  int lane = threadIdx.x;
  int B0   = blockIdx.x * (64 * CHUNK_L);
  int R0   = B0 - WARM_W; if (R0 < 0) R0 = 0;

  const float4* xp4 = (const float4*)xpw;
#pragma unroll
  for (int i = 0; i < STAGE_ROWS / 64; i++) {
    int r = 64 * i + lane;
    lds_xp[phys(r)] = xp4[R0 + r];
  }
  __syncthreads();

  float w20 = -L2E * wr[0];
  float w21 = -L2E * wr[1];
  float w22 = -L2E * wr[2];
  float w23 = -2.f * L2E * wr[3];

  float h = h0p[0], c = c0p[0];

  auto stepc = [&](float4 p) {
    float u0 = fmaf(h, w20, p.x);
    float u1 = fmaf(h, w21, p.y);
    float u2 = fmaf(h, w22, p.z);
    float u3 = fmaf(h, w23, p.w);
    float f  = __builtin_amdgcn_rcpf(1.f + __builtin_amdgcn_exp2f(u0));
    float i  = __builtin_amdgcn_rcpf(1.f + __builtin_amdgcn_exp2f(u1));
    float o  = __builtin_amdgcn_rcpf(1.f + __builtin_amdgcn_exp2f(u2));
    float r3 = __builtin_amdgcn_rcpf(1.f + __builtin_amdgcn_exp2f(u3));
    c = fmaf(f, c, fmaf(2.f * i, r3, -i));           // c = f*c + i*(2*r3-1)
    float rt = __builtin_amdgcn_rcpf(1.f + __builtin_amdgcn_exp2f(c * M2));
    h = fmaf(2.f * o, rt, -o);                       // h = o*tanh(c)
  };

  auto XP = [&](int r) {
    int rc = r < 0 ? 0 : (r > STAGE_ROWS - 1 ? STAGE_ROWS - 1 : r);
    return lds_xp[phys(rc)];
  };

  int start = B0 + lane * CHUNK_L;      // global first output step
  int rr = (start - WARM_W) - R0;       // LDS row index (negative only in block 0)

  float4 p0 = XP(rr), p1 = XP(rr + 1), p2 = XP(rr + 2), p3 = XP(rr + 3);

  for (int s = 0; s < WARM_W; s += 4, rr += 4) {
    float4 n0 = XP(rr + 4), n1 = XP(rr + 5), n2 = XP(rr + 6), n3 = XP(rr + 7);
    if (rr     >= 0) stepc(p0);
    if (rr + 1 >= 0) stepc(p1);
    if (rr + 2 >= 0) stepc(p2);
    if (rr + 3 >= 0) stepc(p3);
    p0 = n0; p1 = n1; p2 = n2; p3 = n3;
  }
#pragma unroll
  for (int gq = 0; gq < CHUNK_L; gq += 4, rr += 4) {
    float4 n0 = XP(rr + 4), n1 = XP(rr + 5), n2 = XP(rr + 6), n3 = XP(rr + 7);
    stepc(p0); lds_h[lane][gq + 0] = h; lds_c[lane][gq + 0] = c;
    stepc(p1); lds_h[lane][gq + 1] = h; lds_c[lane][gq + 1] = c;
    stepc(p2); lds_h[lane][gq + 2] = h; lds_c[lane][gq + 2] = c;
    stepc(p3); lds_h[lane][gq + 3] = h; lds_c[lane][gq + 3] = c;
    p0 = n0; p1 = n1; p2 = n2; p3 = n3;
  }
  __syncthreads();

  float* outq = out;                      // q_t : [0, 32768)
  float* outh = out + T_LEN;              // h_n : [32768, 65537)
  float* outc = out + 2 * T_LEN + 1;      // c_n : [65537, 98306)
  float rw = rgw[0], rb = rgb[0];
#pragma unroll
  for (int k = 0; k < CHUNK_L; k++) {
    int idx = lane + 64 * k;
    float hv = lds_h[idx >> 4][idx & 15];
    float cv = lds_c[idx >> 4][idx & 15];
    outq[B0 + idx]     = fmaf(hv, rw, rb);
    outh[B0 + idx + 1] = hv;
    outc[B0 + idx + 1] = cv;
  }
  if (blockIdx.x == 0 && lane == 0) { outh[0] = h0p[0]; outc[0] = c0p[0]; }
}

extern "C" void kernel_launch(void* const* d_in, const int* in_sizes, int n_in,
                              void* d_out, int out_size, void* d_ws, size_t ws_size,
                              hipStream_t stream) {
  const float* x  = (const float*)d_in[0];
  const float* wi = (const float*)d_in[1];
  const float* wr = (const float*)d_in[2];
  const float* bs = (const float*)d_in[3];
  const float* rw = (const float*)d_in[4];
  const float* rb = (const float*)d_in[5];
  const float* h0 = (const float*)d_in[6];
  const float* c0 = (const float*)d_in[7];
  float* out = (float*)d_out;
  float* xpw = (float*)d_ws;   // (T_LEN x 4) f32 = 512 KB scratch

  gemv_gates<<<GEMV_BLOCKS, 256, 0, stream>>>(x, wi, bs, xpw);
  lstm_scan<<<SCAN_BLOCKS, 64, 0, stream>>>(xpw, wr, rw, rb, h0, c0, out);
}